// Round 1
// baseline (1782.786 us; speedup 1.0000x reference)
//
#include <hip/hip_runtime.h>
#include <math.h>

#define N_NODES 50000
#define E_EDGES 800000
#define E2 (E_EDGES + N_NODES)
#define HID 128
#define HEADS 4
#define OUTC 64
#define DEPTH 4
#define NEG_SLOPE 0.2f
#define LN_EPS 1e-6f

// ---------------- CSR build ----------------

__global__ void k_deg(const int* __restrict__ ei, int* __restrict__ deg) {
    int e = blockIdx.x * 256 + threadIdx.x;
    if (e >= E2) return;
    int d = (e < E_EDGES) ? ei[E_EDGES + e] : (e - E_EDGES);
    atomicAdd(&deg[d], 1);
}

__global__ void k_scan_block(const int* __restrict__ deg, int* __restrict__ partial,
                             int* __restrict__ bsum, int n) {
    __shared__ int sm[1024];
    int i = blockIdx.x * 1024 + threadIdx.x;
    int v = (i < n) ? deg[i] : 0;
    sm[threadIdx.x] = v;
    __syncthreads();
    for (int off = 1; off < 1024; off <<= 1) {
        int t = (threadIdx.x >= off) ? sm[threadIdx.x - off] : 0;
        __syncthreads();
        sm[threadIdx.x] += t;
        __syncthreads();
    }
    if (i < n) partial[i] = sm[threadIdx.x];
    if (threadIdx.x == 1023) bsum[blockIdx.x] = sm[1023];
}

__global__ void k_scan_bsum(int* __restrict__ bsum, int nb) {
    if (threadIdx.x == 0 && blockIdx.x == 0) {
        int run = 0;
        for (int b = 0; b < nb; ++b) { int v = bsum[b]; bsum[b] = run; run += v; }
    }
}

__global__ void k_scan_fix(const int* __restrict__ deg, int* __restrict__ row_ptr,
                           const int* __restrict__ bsum, int n) {
    int i = blockIdx.x * 1024 + threadIdx.x;
    if (i < n) row_ptr[i] = row_ptr[i] - deg[i] + bsum[blockIdx.x];
    if (i == 0) row_ptr[n] = E2;
}

__global__ void k_fill(const int* __restrict__ ei, const int* __restrict__ row_ptr,
                       int* __restrict__ cur, int* __restrict__ csr_src) {
    int e = blockIdx.x * 256 + threadIdx.x;
    if (e >= E2) return;
    int s, d;
    if (e < E_EDGES) { s = ei[e]; d = ei[E_EDGES + e]; } else { s = d = e - E_EDGES; }
    int pos = atomicAdd(&cur[d], 1);
    csr_src[row_ptr[d] + pos] = s;
}

// ---------------- input projection ----------------

__global__ void k_in_proj(const float* __restrict__ x, const float* __restrict__ W,
                          const float* __restrict__ b, float* __restrict__ h) {
    int idx = blockIdx.x * 256 + threadIdx.x;
    if (idx >= N_NODES * HID) return;
    int n = idx >> 7, j = idx & 127;
    const float* xr = x + n * 3;
    h[idx] = b[j] + xr[0] * W[j] + xr[1] * W[HID + j] + xr[2] * W[2 * HID + j];
}

// ---------------- layernorm (one wave per node) ----------------

__global__ __launch_bounds__(64) void k_ln(const float* __restrict__ h,
                                           const float* __restrict__ gamma,
                                           const float* __restrict__ beta,
                                           float* __restrict__ ln) {
    int nd = blockIdx.x, lane = threadIdx.x;
    const float* row = h + (size_t)nd * HID;
    float a = row[lane], b = row[lane + 64];
    float s = a + b;
    for (int o = 1; o < 64; o <<= 1) s += __shfl_xor(s, o);
    float mu = s * (1.0f / 128.0f);
    float da = a - mu, db = b - mu;
    float v = da * da + db * db;
    for (int o = 1; o < 64; o <<= 1) v += __shfl_xor(v, o);
    float rstd = rsqrtf(v * (1.0f / 128.0f) + LN_EPS);
    float* out = ln + (size_t)nd * HID;
    out[lane]      = da * rstd * gamma[lane]      + beta[lane];
    out[lane + 64] = db * rstd * gamma[lane + 64] + beta[lane + 64];
}

// ---------------- GEMM [N,128] x [128,512] fp32, 64x64 tile ----------------

__global__ __launch_bounds__(256) void k_gemm(const float* __restrict__ A,
                                              const float* __restrict__ B,
                                              float* __restrict__ C) {
    __shared__ float As[64][128];
    __shared__ float Bs[128][64];
    int tid = threadIdx.x;
    int row0 = blockIdx.x * 64;
    int col0 = blockIdx.y * 64;

    for (int it = 0; it < 8; ++it) {
        int flat = tid + it * 256;      // 0..2047 float4 units
        int r = flat >> 5;
        int k4 = (flat & 31) * 4;
        float4 v = make_float4(0.f, 0.f, 0.f, 0.f);
        int gr = row0 + r;
        if (gr < N_NODES) v = *(const float4*)(A + (size_t)gr * HID + k4);
        *(float4*)&As[r][k4] = v;
    }
    for (int it = 0; it < 8; ++it) {
        int flat = tid + it * 256;
        int k = flat >> 4;
        int j4 = (flat & 15) * 4;
        *(float4*)&Bs[k][j4] = *(const float4*)(B + (size_t)k * 512 + col0 + j4);
    }
    __syncthreads();

    int r0 = (tid >> 4) * 4;
    int c0 = (tid & 15) * 4;
    float acc[4][4];
    for (int i = 0; i < 4; ++i)
        for (int j = 0; j < 4; ++j) acc[i][j] = 0.f;

    for (int k0 = 0; k0 < 128; k0 += 4) {
        float4 a0 = *(float4*)&As[r0 + 0][k0];
        float4 a1 = *(float4*)&As[r0 + 1][k0];
        float4 a2 = *(float4*)&As[r0 + 2][k0];
        float4 a3 = *(float4*)&As[r0 + 3][k0];
        const float* ap0 = (const float*)&a0;
        const float* ap1 = (const float*)&a1;
        const float* ap2 = (const float*)&a2;
        const float* ap3 = (const float*)&a3;
        for (int kk = 0; kk < 4; ++kk) {
            float4 b = *(float4*)&Bs[k0 + kk][c0];
            float bv[4] = {b.x, b.y, b.z, b.w};
            for (int j = 0; j < 4; ++j) {
                acc[0][j] += ap0[kk] * bv[j];
                acc[1][j] += ap1[kk] * bv[j];
                acc[2][j] += ap2[kk] * bv[j];
                acc[3][j] += ap3[kk] * bv[j];
            }
        }
    }
    for (int i = 0; i < 4; ++i) {
        int gr = row0 + r0 + i;
        if (gr < N_NODES) {
            float4 v = make_float4(acc[i][0], acc[i][1], acc[i][2], acc[i][3]);
            *(float4*)(C + (size_t)gr * 512 + col0 + c0) = v;
        }
    }
}

// ---------------- alpha_s / alpha_d dots (one wave per node) ----------------

__global__ __launch_bounds__(64) void k_alpha(const float* __restrict__ xh,
                                              const float* __restrict__ att_s,
                                              const float* __restrict__ att_d,
                                              float* __restrict__ as_,
                                              float* __restrict__ ad_) {
    int nd = blockIdx.x, lane = threadIdx.x;
    int h = lane >> 4;
    int cb = (lane & 15) * 8;
    const float* xr = xh + (size_t)nd * 512 + lane * 8;
    float4 xa = *(const float4*)(xr);
    float4 xb = *(const float4*)(xr + 4);
    const float* asr = att_s + h * HID + cb;
    const float* adr = att_d + h * HID + cb;
    float s = xa.x * asr[0] + xa.y * asr[1] + xa.z * asr[2] + xa.w * asr[3]
            + xb.x * asr[4] + xb.y * asr[5] + xb.z * asr[6] + xb.w * asr[7];
    float d = xa.x * adr[0] + xa.y * adr[1] + xa.z * adr[2] + xa.w * adr[3]
            + xb.x * adr[4] + xb.y * adr[5] + xb.z * adr[6] + xb.w * adr[7];
    for (int o = 1; o < 16; o <<= 1) { s += __shfl_xor(s, o); d += __shfl_xor(d, o); }
    if ((lane & 15) == 0) {
        as_[nd * HEADS + h] = s;
        ad_[nd * HEADS + h] = d;
    }
}

// ---------------- per-node softmax-aggregate + mean + bias + relu + residual ----------------

__global__ __launch_bounds__(64) void k_agg(const float* __restrict__ xh,
                                            const float* __restrict__ as_,
                                            const float* __restrict__ ad_,
                                            const int* __restrict__ row_ptr,
                                            const int* __restrict__ csr_src,
                                            const float* __restrict__ bias,
                                            float* __restrict__ h) {
    int nd = blockIdx.x, lane = threadIdx.x;
    int start = row_ptr[nd], end = row_ptr[nd + 1];
    float4 adv = *(const float4*)(ad_ + nd * 4);
    float ad[4] = {adv.x, adv.y, adv.z, adv.w};
    float m[4] = {-1e30f, -1e30f, -1e30f, -1e30f};

    for (int e = start + lane; e < end; e += 64) {
        int s = csr_src[e];
        float4 asv = *(const float4*)(as_ + s * 4);
        float vs[4] = {asv.x, asv.y, asv.z, asv.w};
        for (int hh = 0; hh < 4; ++hh) {
            float v = vs[hh] + ad[hh];
            v = (v >= 0.f) ? v : NEG_SLOPE * v;
            m[hh] = fmaxf(m[hh], v);
        }
    }
    for (int o = 1; o < 64; o <<= 1)
        for (int hh = 0; hh < 4; ++hh) m[hh] = fmaxf(m[hh], __shfl_xor(m[hh], o));

    int hh = lane >> 4;
    float mh = m[hh], adh = ad[hh];
    float acc[8] = {0, 0, 0, 0, 0, 0, 0, 0};
    float z = 0.f;
    for (int e = start; e < end; ++e) {
        int s = csr_src[e];
        float v = as_[s * 4 + hh] + adh;
        v = (v >= 0.f) ? v : NEG_SLOPE * v;
        float p = __expf(v - mh);
        z += p;
        const float4* xr = (const float4*)(xh + (size_t)s * 512 + lane * 8);
        float4 xa = xr[0], xb = xr[1];
        acc[0] += p * xa.x; acc[1] += p * xa.y; acc[2] += p * xa.z; acc[3] += p * xa.w;
        acc[4] += p * xb.x; acc[5] += p * xb.y; acc[6] += p * xb.z; acc[7] += p * xb.w;
    }
    float inv = 1.0f / z;
    for (int j = 0; j < 8; ++j) acc[j] *= inv;
    for (int j = 0; j < 8; ++j) acc[j] += __shfl_xor(acc[j], 16);
    for (int j = 0; j < 8; ++j) acc[j] += __shfl_xor(acc[j], 32);

    if (lane < 16) {
        int c = lane * 8;
        float* hr = h + (size_t)nd * HID + c;
        const float* br = bias + c;
        float r[8];
        for (int j = 0; j < 8; ++j) {
            float t = 0.25f * acc[j] + br[j];
            t = fmaxf(t, 0.f);
            r[j] = t + hr[j];
        }
        *(float4*)(hr)     = make_float4(r[0], r[1], r[2], r[3]);
        *(float4*)(hr + 4) = make_float4(r[4], r[5], r[6], r[7]);
    }
}

// ---------------- output projection ----------------

__global__ __launch_bounds__(64) void k_out_proj(const float* __restrict__ h,
                                                 const float* __restrict__ W,
                                                 const float* __restrict__ b,
                                                 float* __restrict__ out) {
    int n = blockIdx.x, j = threadIdx.x;
    const float* hr = h + (size_t)n * HID;
    float acc = b[j];
    for (int k = 0; k < HID; ++k) acc += hr[k] * W[k * OUTC + j];
    out[(size_t)n * OUTC + j] = acc;
}

// ---------------- launch ----------------

extern "C" void kernel_launch(void* const* d_in, const int* in_sizes, int n_in,
                              void* d_out, int out_size, void* d_ws, size_t ws_size,
                              hipStream_t stream) {
    const float* x       = (const float*)d_in[0];
    const int*   ei      = (const int*)d_in[1];
    const float* W_in    = (const float*)d_in[2];
    const float* b_in    = (const float*)d_in[3];
    const float* W_conv  = (const float*)d_in[4];
    const float* att_src = (const float*)d_in[5];
    const float* att_dst = (const float*)d_in[6];
    const float* b_conv  = (const float*)d_in[7];
    const float* ln_g    = (const float*)d_in[8];
    const float* ln_b    = (const float*)d_in[9];
    const float* W_out   = (const float*)d_in[10];
    const float* b_out   = (const float*)d_in[11];
    float* out = (float*)d_out;

    char* ws = (char*)d_ws;
    size_t off = 0;
    auto alloc = [&](size_t bytes) { void* p = ws + off; off = (off + bytes + 255) & ~(size_t)255; return p; };
    float* h    = (float*)alloc((size_t)N_NODES * HID * 4);
    float* ln   = (float*)alloc((size_t)N_NODES * HID * 4);
    float* xh   = (float*)alloc((size_t)N_NODES * 512 * 4);
    float* as_  = (float*)alloc((size_t)N_NODES * HEADS * 4);
    float* ad_  = (float*)alloc((size_t)N_NODES * HEADS * 4);
    int* deg    = (int*)alloc((size_t)N_NODES * 4);
    int* cur    = (int*)alloc((size_t)N_NODES * 4);
    int* row_ptr= (int*)alloc((size_t)(N_NODES + 1) * 4);
    int* csr    = (int*)alloc((size_t)E2 * 4);
    int* bsum   = (int*)alloc(256 * 4);
    (void)ws_size; (void)n_in; (void)in_sizes; (void)out_size;

    hipMemsetAsync(deg, 0, (size_t)N_NODES * 4, stream);
    hipMemsetAsync(cur, 0, (size_t)N_NODES * 4, stream);

    // CSR build
    k_deg<<<(E2 + 255) / 256, 256, 0, stream>>>(ei, deg);
    int nb = (N_NODES + 1023) / 1024;
    k_scan_block<<<nb, 1024, 0, stream>>>(deg, row_ptr, bsum, N_NODES);
    k_scan_bsum<<<1, 64, 0, stream>>>(bsum, nb);
    k_scan_fix<<<nb, 1024, 0, stream>>>(deg, row_ptr, bsum, N_NODES);
    k_fill<<<(E2 + 255) / 256, 256, 0, stream>>>(ei, row_ptr, cur, csr);

    // input projection
    k_in_proj<<<(N_NODES * HID + 255) / 256, 256, 0, stream>>>(x, W_in, b_in, h);

    // layers
    for (int i = 0; i < DEPTH; ++i) {
        const float* Wc = W_conv + (size_t)i * HID * HEADS * HID;
        const float* asp = att_src + (size_t)i * HEADS * HID;
        const float* adp = att_dst + (size_t)i * HEADS * HID;
        const float* bcp = b_conv + (size_t)i * HID;
        const float* gp = ln_g + (size_t)i * HID;
        const float* bp = ln_b + (size_t)i * HID;

        k_ln<<<N_NODES, 64, 0, stream>>>(h, gp, bp, ln);
        dim3 gg((N_NODES + 63) / 64, 8);
        k_gemm<<<gg, 256, 0, stream>>>(ln, Wc, xh);
        k_alpha<<<N_NODES, 64, 0, stream>>>(xh, asp, adp, as_, ad_);
        k_agg<<<N_NODES, 64, 0, stream>>>(xh, as_, ad_, row_ptr, csr, bcp, h);
    }

    k_out_proj<<<N_NODES, 64, 0, stream>>>(h, W_out, b_out, out);
}

// Round 2
// 1059.496 us; speedup vs baseline: 1.6827x; 1.6827x over previous
//
#include <hip/hip_runtime.h>
#include <hip/hip_fp16.h>
#include <math.h>

#define N_NODES 50000
#define E_EDGES 800000
#define E2 (E_EDGES + N_NODES)
#define HID 128
#define HEADS 4
#define OUTC 64
#define DEPTH 4
#define NEG_SLOPE 0.2f
#define LN_EPS 1e-6f

typedef float f32x4 __attribute__((ext_vector_type(4)));
typedef short short8 __attribute__((ext_vector_type(8)));

static __device__ inline unsigned short f2bf(float x) {
    unsigned int u = __float_as_uint(x);
    unsigned int r = (u + 0x7fffu + ((u >> 16) & 1u)) >> 16;
    return (unsigned short)r;
}
static __device__ inline float bf2f(unsigned short s) {
    return __uint_as_float(((unsigned int)s) << 16);
}

// ---------------- CSR build ----------------

__global__ void k_deg(const int* __restrict__ ei, int* __restrict__ deg) {
    int e = blockIdx.x * 256 + threadIdx.x;
    if (e >= E2) return;
    int d = (e < E_EDGES) ? ei[E_EDGES + e] : (e - E_EDGES);
    atomicAdd(&deg[d], 1);
}

__global__ void k_scan_block(const int* __restrict__ deg, int* __restrict__ partial,
                             int* __restrict__ bsum, int n) {
    __shared__ int sm[1024];
    int i = blockIdx.x * 1024 + threadIdx.x;
    int v = (i < n) ? deg[i] : 0;
    sm[threadIdx.x] = v;
    __syncthreads();
    for (int off = 1; off < 1024; off <<= 1) {
        int t = (threadIdx.x >= off) ? sm[threadIdx.x - off] : 0;
        __syncthreads();
        sm[threadIdx.x] += t;
        __syncthreads();
    }
    if (i < n) partial[i] = sm[threadIdx.x];
    if (threadIdx.x == 1023) bsum[blockIdx.x] = sm[1023];
}

__global__ void k_scan_bsum(int* __restrict__ bsum, int nb) {
    if (threadIdx.x == 0 && blockIdx.x == 0) {
        int run = 0;
        for (int b = 0; b < nb; ++b) { int v = bsum[b]; bsum[b] = run; run += v; }
    }
}

__global__ void k_scan_fix(const int* __restrict__ deg, int* __restrict__ row_ptr,
                           const int* __restrict__ bsum, int n) {
    int i = blockIdx.x * 1024 + threadIdx.x;
    if (i < n) row_ptr[i] = row_ptr[i] - deg[i] + bsum[blockIdx.x];
    if (i == 0) row_ptr[n] = E2;
}

__global__ void k_fill(const int* __restrict__ ei, const int* __restrict__ row_ptr,
                       int* __restrict__ cur, int* __restrict__ csr_src) {
    int e = blockIdx.x * 256 + threadIdx.x;
    if (e >= E2) return;
    int s, d;
    if (e < E_EDGES) { s = ei[e]; d = ei[E_EDGES + e]; } else { s = d = e - E_EDGES; }
    int pos = atomicAdd(&cur[d], 1);
    csr_src[row_ptr[d] + pos] = s;
}

// ---------------- input projection ----------------

__global__ void k_in_proj(const float* __restrict__ x, const float* __restrict__ W,
                          const float* __restrict__ b, float* __restrict__ h) {
    int idx = blockIdx.x * 256 + threadIdx.x;
    if (idx >= N_NODES * HID) return;
    int n = idx >> 7, j = idx & 127;
    const float* xr = x + n * 3;
    h[idx] = b[j] + xr[0] * W[j] + xr[1] * W[HID + j] + xr[2] * W[2 * HID + j];
}

// ---------------- layernorm -> split bf16 hi/lo (one wave per node) ----------------

__global__ __launch_bounds__(64) void k_ln(const float* __restrict__ h,
                                           const float* __restrict__ gamma,
                                           const float* __restrict__ beta,
                                           unsigned short* __restrict__ ln_hi,
                                           unsigned short* __restrict__ ln_lo) {
    int nd = blockIdx.x, lane = threadIdx.x;
    const float* row = h + (size_t)nd * HID;
    float a = row[lane], b = row[lane + 64];
    float s = a + b;
    for (int o = 1; o < 64; o <<= 1) s += __shfl_xor(s, o);
    float mu = s * (1.0f / 128.0f);
    float da = a - mu, db = b - mu;
    float v = da * da + db * db;
    for (int o = 1; o < 64; o <<= 1) v += __shfl_xor(v, o);
    float rstd = rsqrtf(v * (1.0f / 128.0f) + LN_EPS);
    float va = da * rstd * gamma[lane]      + beta[lane];
    float vb = db * rstd * gamma[lane + 64] + beta[lane + 64];
    size_t base = (size_t)nd * HID;
    unsigned short ha = f2bf(va), hb = f2bf(vb);
    ln_hi[base + lane]      = ha;
    ln_hi[base + lane + 64] = hb;
    ln_lo[base + lane]      = f2bf(va - bf2f(ha));
    ln_lo[base + lane + 64] = f2bf(vb - bf2f(hb));
}

// ---------------- repack W_conv into MFMA B-fragment layout (hi/lo bf16) ----------------
// Bp[layer][ntile(32)][kc(4)][lane(64)][j(8)]; k = kc*32 + (lane>>4)*8 + j, n = ntile*16 + (lane&15)

__global__ void k_repackB(const float* __restrict__ W_conv,
                          unsigned short* __restrict__ Bp_hi,
                          unsigned short* __restrict__ Bp_lo) {
    int idx = blockIdx.x * 256 + threadIdx.x;
    if (idx >= DEPTH * 65536) return;
    int j     = idx & 7;
    int lane  = (idx >> 3) & 63;
    int kc    = (idx >> 9) & 3;
    int ntile = (idx >> 11) & 31;
    int layer = idx >> 16;
    int k = kc * 32 + (lane >> 4) * 8 + j;
    int n = ntile * 16 + (lane & 15);
    float w = W_conv[(size_t)layer * 65536 + (size_t)k * 512 + n];
    unsigned short hi = f2bf(w);
    Bp_hi[idx] = hi;
    Bp_lo[idx] = f2bf(w - bf2f(hi));
}

// ---------------- MFMA GEMM: [N,128](bf16 hi/lo) x [128,512](bf16 hi/lo) -> xh fp16 ----------------
// one wave per 64x64 C tile; no LDS. bf16x3: Ahi*Bhi + Ahi*Blo + Alo*Bhi.

__global__ __launch_bounds__(64) void k_gemm_mfma(const unsigned short* __restrict__ ln_hi,
                                                  const unsigned short* __restrict__ ln_lo,
                                                  const unsigned short* __restrict__ Bp_hi,
                                                  const unsigned short* __restrict__ Bp_lo,
                                                  __half* __restrict__ xh) {
    int lane = threadIdx.x;
    int row0 = blockIdx.x * 64;
    int by   = blockIdx.y;           // col block of 64 (4 ntiles)
    int quad = lane >> 4;
    int l15  = lane & 15;

    f32x4 acc[4][4];
    for (int mt = 0; mt < 4; ++mt)
        for (int nt = 0; nt < 4; ++nt)
            acc[mt][nt] = (f32x4)(0.0f);

    for (int kc = 0; kc < 4; ++kc) {
        short8 ah[4], al[4], bh[4], bl[4];
        for (int mt = 0; mt < 4; ++mt) {
            int row = row0 + mt * 16 + l15;
            if (row >= N_NODES) row = N_NODES - 1;   // clamp; stores guarded
            size_t off = (size_t)row * 128 + kc * 32 + quad * 8;
            ah[mt] = *(const short8*)(ln_hi + off);
            al[mt] = *(const short8*)(ln_lo + off);
        }
        for (int nt = 0; nt < 4; ++nt) {
            size_t off = ((size_t)((by * 4 + nt) * 4 + kc) * 64 + lane) * 8;
            bh[nt] = *(const short8*)(Bp_hi + off);
            bl[nt] = *(const short8*)(Bp_lo + off);
        }
        for (int mt = 0; mt < 4; ++mt)
            for (int nt = 0; nt < 4; ++nt) {
                acc[mt][nt] = __builtin_amdgcn_mfma_f32_16x16x32_bf16(ah[mt], bh[nt], acc[mt][nt], 0, 0, 0);
                acc[mt][nt] = __builtin_amdgcn_mfma_f32_16x16x32_bf16(ah[mt], bl[nt], acc[mt][nt], 0, 0, 0);
                acc[mt][nt] = __builtin_amdgcn_mfma_f32_16x16x32_bf16(al[mt], bh[nt], acc[mt][nt], 0, 0, 0);
            }
    }

    // C/D layout: col = l15 (+tile), row = quad*4 + reg (+tile)
    int col0 = by * 64;
    for (int mt = 0; mt < 4; ++mt) {
        for (int r = 0; r < 4; ++r) {
            int row = row0 + mt * 16 + quad * 4 + r;
            if (row >= N_NODES) continue;
            __half* dst = xh + (size_t)row * 512 + col0 + l15;
            for (int nt = 0; nt < 4; ++nt)
                dst[nt * 16] = __float2half(acc[mt][nt][r]);
        }
    }
}

// ---------------- alpha_s / alpha_d dots (one wave per node, xh fp16) ----------------

__global__ __launch_bounds__(64) void k_alpha(const __half* __restrict__ xh,
                                              const float* __restrict__ att_s,
                                              const float* __restrict__ att_d,
                                              float* __restrict__ as_,
                                              float* __restrict__ ad_) {
    int nd = blockIdx.x, lane = threadIdx.x;
    int h = lane >> 4;
    int cb = (lane & 15) * 8;
    union { float4 f4; __half hv[8]; } u;
    u.f4 = *(const float4*)(xh + (size_t)nd * 512 + lane * 8);
    const float* asr = att_s + h * HID + cb;
    const float* adr = att_d + h * HID + cb;
    float s = 0.f, d = 0.f;
    for (int j = 0; j < 8; ++j) {
        float xv = __half2float(u.hv[j]);
        s += xv * asr[j];
        d += xv * adr[j];
    }
    for (int o = 1; o < 16; o <<= 1) { s += __shfl_xor(s, o); d += __shfl_xor(d, o); }
    if ((lane & 15) == 0) {
        as_[nd * HEADS + h] = s;
        ad_[nd * HEADS + h] = d;
    }
}

// ---------------- per-node softmax-aggregate + mean + bias + relu + residual ----------------

__global__ __launch_bounds__(64) void k_agg(const __half* __restrict__ xh,
                                            const float* __restrict__ as_,
                                            const float* __restrict__ ad_,
                                            const int* __restrict__ row_ptr,
                                            const int* __restrict__ csr_src,
                                            const float* __restrict__ bias,
                                            float* __restrict__ h) {
    int nd = blockIdx.x, lane = threadIdx.x;
    int start = row_ptr[nd], end = row_ptr[nd + 1];
    float4 adv = *(const float4*)(ad_ + nd * 4);
    float ad[4] = {adv.x, adv.y, adv.z, adv.w};
    float m[4] = {-1e30f, -1e30f, -1e30f, -1e30f};

    for (int e = start + lane; e < end; e += 64) {
        int s = csr_src[e];
        float4 asv = *(const float4*)(as_ + s * 4);
        float vs[4] = {asv.x, asv.y, asv.z, asv.w};
        for (int hh = 0; hh < 4; ++hh) {
            float v = vs[hh] + ad[hh];
            v = (v >= 0.f) ? v : NEG_SLOPE * v;
            m[hh] = fmaxf(m[hh], v);
        }
    }
    for (int o = 1; o < 64; o <<= 1)
        for (int hh = 0; hh < 4; ++hh) m[hh] = fmaxf(m[hh], __shfl_xor(m[hh], o));

    int hh = lane >> 4;
    float mh = m[hh], adh = ad[hh];
    float acc[8] = {0, 0, 0, 0, 0, 0, 0, 0};
    float z = 0.f;
    for (int e = start; e < end; ++e) {
        int s = csr_src[e];
        float v = as_[s * 4 + hh] + adh;
        v = (v >= 0.f) ? v : NEG_SLOPE * v;
        float p = __expf(v - mh);
        z += p;
        union { float4 f4; __half hv[8]; } u;
        u.f4 = *(const float4*)(xh + (size_t)s * 512 + lane * 8);
        acc[0] += p * __half2float(u.hv[0]);
        acc[1] += p * __half2float(u.hv[1]);
        acc[2] += p * __half2float(u.hv[2]);
        acc[3] += p * __half2float(u.hv[3]);
        acc[4] += p * __half2float(u.hv[4]);
        acc[5] += p * __half2float(u.hv[5]);
        acc[6] += p * __half2float(u.hv[6]);
        acc[7] += p * __half2float(u.hv[7]);
    }
    float inv = 1.0f / z;
    for (int j = 0; j < 8; ++j) acc[j] *= inv;
    for (int j = 0; j < 8; ++j) acc[j] += __shfl_xor(acc[j], 16);
    for (int j = 0; j < 8; ++j) acc[j] += __shfl_xor(acc[j], 32);

    if (lane < 16) {
        int c = lane * 8;
        float* hr = h + (size_t)nd * HID + c;
        const float* br = bias + c;
        float r[8];
        for (int j = 0; j < 8; ++j) {
            float t = 0.25f * acc[j] + br[j];
            t = fmaxf(t, 0.f);
            r[j] = t + hr[j];
        }
        *(float4*)(hr)     = make_float4(r[0], r[1], r[2], r[3]);
        *(float4*)(hr + 4) = make_float4(r[4], r[5], r[6], r[7]);
    }
}

// ---------------- output projection ----------------

__global__ __launch_bounds__(64) void k_out_proj(const float* __restrict__ h,
                                                 const float* __restrict__ W,
                                                 const float* __restrict__ b,
                                                 float* __restrict__ out) {
    int n = blockIdx.x, j = threadIdx.x;
    const float* hr = h + (size_t)n * HID;
    float acc = b[j];
    for (int k = 0; k < HID; ++k) acc += hr[k] * W[k * OUTC + j];
    out[(size_t)n * OUTC + j] = acc;
}

// ---------------- launch ----------------

extern "C" void kernel_launch(void* const* d_in, const int* in_sizes, int n_in,
                              void* d_out, int out_size, void* d_ws, size_t ws_size,
                              hipStream_t stream) {
    const float* x       = (const float*)d_in[0];
    const int*   ei      = (const int*)d_in[1];
    const float* W_in    = (const float*)d_in[2];
    const float* b_in    = (const float*)d_in[3];
    const float* W_conv  = (const float*)d_in[4];
    const float* att_src = (const float*)d_in[5];
    const float* att_dst = (const float*)d_in[6];
    const float* b_conv  = (const float*)d_in[7];
    const float* ln_g    = (const float*)d_in[8];
    const float* ln_b    = (const float*)d_in[9];
    const float* W_out   = (const float*)d_in[10];
    const float* b_out   = (const float*)d_in[11];
    float* out = (float*)d_out;

    char* ws = (char*)d_ws;
    size_t off = 0;
    auto alloc = [&](size_t bytes) { void* p = ws + off; off = (off + bytes + 255) & ~(size_t)255; return p; };
    float* h            = (float*)alloc((size_t)N_NODES * HID * 4);
    unsigned short* lhi = (unsigned short*)alloc((size_t)N_NODES * HID * 2);
    unsigned short* llo = (unsigned short*)alloc((size_t)N_NODES * HID * 2);
    __half* xh          = (__half*)alloc((size_t)N_NODES * 512 * 2);
    float* as_          = (float*)alloc((size_t)N_NODES * HEADS * 4);
    float* ad_          = (float*)alloc((size_t)N_NODES * HEADS * 4);
    unsigned short* Bph = (unsigned short*)alloc((size_t)DEPTH * 65536 * 2);
    unsigned short* Bpl = (unsigned short*)alloc((size_t)DEPTH * 65536 * 2);
    int* deg    = (int*)alloc((size_t)N_NODES * 4);
    int* cur    = (int*)alloc((size_t)N_NODES * 4);
    int* row_ptr= (int*)alloc((size_t)(N_NODES + 1) * 4);
    int* csr    = (int*)alloc((size_t)E2 * 4);
    int* bsum   = (int*)alloc(256 * 4);
    (void)ws_size; (void)n_in; (void)in_sizes; (void)out_size;

    hipMemsetAsync(deg, 0, (size_t)N_NODES * 4, stream);
    hipMemsetAsync(cur, 0, (size_t)N_NODES * 4, stream);

    // CSR build
    k_deg<<<(E2 + 255) / 256, 256, 0, stream>>>(ei, deg);
    int nb = (N_NODES + 1023) / 1024;
    k_scan_block<<<nb, 1024, 0, stream>>>(deg, row_ptr, bsum, N_NODES);
    k_scan_bsum<<<1, 64, 0, stream>>>(bsum, nb);
    k_scan_fix<<<nb, 1024, 0, stream>>>(deg, row_ptr, bsum, N_NODES);
    k_fill<<<(E2 + 255) / 256, 256, 0, stream>>>(ei, row_ptr, cur, csr);

    // weight repack (per call; graph-safe)
    k_repackB<<<(DEPTH * 65536 + 255) / 256, 256, 0, stream>>>(W_conv, Bph, Bpl);

    // input projection
    k_in_proj<<<(N_NODES * HID + 255) / 256, 256, 0, stream>>>(x, W_in, b_in, h);

    // layers
    for (int i = 0; i < DEPTH; ++i) {
        const float* asp = att_src + (size_t)i * HEADS * HID;
        const float* adp = att_dst + (size_t)i * HEADS * HID;
        const float* bcp = b_conv + (size_t)i * HID;
        const float* gp = ln_g + (size_t)i * HID;
        const float* bp = ln_b + (size_t)i * HID;

        k_ln<<<N_NODES, 64, 0, stream>>>(h, gp, bp, lhi, llo);
        dim3 gg((N_NODES + 63) / 64, 8);
        k_gemm_mfma<<<gg, 64, 0, stream>>>(lhi, llo, Bph + (size_t)i * 65536,
                                           Bpl + (size_t)i * 65536, xh);
        k_alpha<<<N_NODES, 64, 0, stream>>>(xh, asp, adp, as_, ad_);
        k_agg<<<N_NODES, 64, 0, stream>>>(xh, as_, ad_, row_ptr, csr, bcp, h);
    }

    k_out_proj<<<N_NODES, 64, 0, stream>>>(h, W_out, b_out, out);
}